// Round 29
// baseline (886.730 us; speedup 1.0000x reference)
//
#include <hip/hip_runtime.h>
#include <hip/hip_bf16.h>
#include <math.h>

// RULPredictionModel: B=16 S=1024 D=384 H=8 DH=48 L=3 E=8 FF=768 TOP_K=2
#define TOKENS 16384
#define DMODEL 384
#define SEQ 1024
#define NHEAD 8
#define DHEAD 48
#define NEXP 8
#define FFDIM 768
#define NL 3

typedef __bf16 bf16x8 __attribute__((ext_vector_type(8)));
typedef __bf16 bf16x4 __attribute__((ext_vector_type(4)));
typedef float f32x4 __attribute__((ext_vector_type(4)));

// ---------------- tiny kernels ----------------
// finalize: total_moe from per-layer counts/sum_probs
__global__ void finalize_kernel(const int* __restrict__ counts_all,
                                const float* __restrict__ sp_all, float* __restrict__ out) {
  float tm = 0.f;
  for (int l = 0; l < NL; l++) {
    float t = 0.f;
    for (int e = 0; e < NEXP; e++)
      t += sp_all[l * NEXP + e] * (float)counts_all[l * NEXP + e];
    tm += (float)NEXP * t / ((float)TOKENS * (float)TOKENS);
  }
  out[16] = tm;
}

__global__ __launch_bounds__(256) void proj_kernel(const float* __restrict__ x,
    const float* __restrict__ pw, const float* __restrict__ pb, float* __restrict__ h) {
  int i = blockIdx.x * 256 + threadIdx.x;
  int t = i / DMODEL;
  int d = i - t * DMODEL;
  h[i] = x[t] * pw[d] + pb[d];
}

// weight transpose + cast: src fp32 [K][N] (batched) -> dst bf16 [N][K]
__global__ __launch_bounds__(256) void convw_kernel(const float* __restrict__ src,
    __bf16* __restrict__ dst, int K, int N) {
  __shared__ float t[32][33];
  size_t boff = (size_t)blockIdx.z * K * N;
  src += boff; dst += boff;
  int k0 = blockIdx.y * 32, n0 = blockIdx.x * 32;
  int tx = threadIdx.x & 31, ty = threadIdx.x >> 5;   // 32 x 8
#pragma unroll
  for (int i = 0; i < 32; i += 8) t[ty + i][tx] = src[(size_t)(k0 + ty + i) * N + n0 + tx];
  __syncthreads();
#pragma unroll
  for (int i = 0; i < 32; i += 8)
    dst[(size_t)(n0 + ty + i) * K + k0 + tx] = (__bf16)t[tx][ty + i];
}

// one block (384 threads) per row; bf16 output.
// If zc/zs non-null, block 0 zeroes that layer's counts/sum_probs slice
// (gate runs strictly after this kernel in stream order).
__global__ __launch_bounds__(384) void ln_kernel(const float* __restrict__ src,
    __bf16* __restrict__ dst, const float* __restrict__ gs, const float* __restrict__ gb,
    int* __restrict__ zc, float* __restrict__ zs) {
  int row = blockIdx.x, tid = threadIdx.x;
  if (zc && row == 0 && tid < NEXP) { zc[tid] = 0; zs[tid] = 0.f; }
  float v = src[(size_t)row * DMODEL + tid];
  float sum = v, sq = v * v;
#pragma unroll
  for (int off = 32; off; off >>= 1) { sum += __shfl_xor(sum, off); sq += __shfl_xor(sq, off); }
  __shared__ float rs[6], rq[6];
  __shared__ float smean, sinv;
  int wid = tid >> 6;
  if ((tid & 63) == 0) { rs[wid] = sum; rq[wid] = sq; }
  __syncthreads();
  if (tid == 0) {
    float S = 0.f, Q = 0.f;
    for (int w = 0; w < 6; w++) { S += rs[w]; Q += rq[w]; }
    float mean = S / (float)DMODEL;
    float var = Q / (float)DMODEL - mean * mean;
    smean = mean; sinv = rsqrtf(var + 1e-5f);
  }
  __syncthreads();
  dst[(size_t)row * DMODEL + tid] = (__bf16)((v - smean) * sinv * gs[tid] + gb[tid]);
}

// fused combine + layernorm: h += ab0+ab1; dst = LN(h)  (one h pass saved)
__global__ __launch_bounds__(384) void lncomb_kernel(float* __restrict__ h,
    const __bf16* __restrict__ ab, __bf16* __restrict__ dst,
    const float* __restrict__ gs, const float* __restrict__ gb) {
  int row = blockIdx.x, tid = threadIdx.x;
  size_t idx = (size_t)row * DMODEL + tid;
  float v = h[idx] + (float)ab[idx] + (float)ab[(size_t)TOKENS * DMODEL + idx];
  h[idx] = v;
  float sum = v, sq = v * v;
#pragma unroll
  for (int off = 32; off; off >>= 1) { sum += __shfl_xor(sum, off); sq += __shfl_xor(sq, off); }
  __shared__ float rs[6], rq[6];
  __shared__ float smean, sinv;
  int wid = tid >> 6;
  if ((tid & 63) == 0) { rs[wid] = sum; rq[wid] = sq; }
  __syncthreads();
  if (tid == 0) {
    float S = 0.f, Q = 0.f;
    for (int w = 0; w < 6; w++) { S += rs[w]; Q += rq[w]; }
    float mean = S / (float)DMODEL;
    float var = Q / (float)DMODEL - mean * mean;
    smean = mean; sinv = rsqrtf(var + 1e-5f);
  }
  __syncthreads();
  dst[idx] = (__bf16)((v - smean) * sinv * gs[tid] + gb[tid]);
}

// ---------------- bf16 MFMA GEMM: C = A @ Wt^T + bias, tile 128x128x64 ----------------
// A-path LDS bypass (r28 win) + HALF-TILE EPILOGUE: LDS = Bs only (18.4 KB),
// epilogue stages C in two 64-row phases reusing the Bs region ->
// blocks/CU rises 4 -> 6 (VGPR-capped), +50% occupancy for latency hiding.
// MODE 0: qkv   (A=xnb, writes head-major (scale*log2e)*Qh / Kh + transposed VTh)
// MODE 1: out   (A=aob,  Cf += acc+bias)   [residual]
// MODE 2: moe1  (A=gather(xnb) via tok_list&0xFFFF, relu, out bf16 a1)
// MODE 3: moe2  (A=a1b rows base+m, gated; out bf16 ab[a][t])
template<int MODE>
__global__ __launch_bounds__(256) void mgemm_kernel(
    const __bf16* __restrict__ Abf, const __bf16* __restrict__ Wt,
    const float* __restrict__ bias, float* __restrict__ Cf, __bf16* __restrict__ Cb,
    __bf16* __restrict__ pQ, __bf16* __restrict__ pK, __bf16* __restrict__ pV,
    const int* __restrict__ counts,
    const int* __restrict__ tok_list, const float* __restrict__ gate_list,
    int N, int K) {
  int e = 0, cnt = 0, base = 0;
  const int* tl = nullptr;
  int m0 = blockIdx.y * 128;
  int n0 = blockIdx.x * 128;
  if constexpr (MODE == 2 || MODE == 3) {
    e = blockIdx.z;
    cnt = counts[e];
    if (m0 >= cnt) return;
    for (int i = 0; i < NEXP; i++) {          // inline 64-padded prefix offset
      int ci = counts[i];
      if (i < e) base += (ci + 63) & ~63;
    }
    tl = tok_list + e * TOKENS;
    Wt += (size_t)e * N * K;
    bias += (size_t)e * N;
  }
  __shared__ __align__(16) __bf16 smem[128][72];      // Bs only: 18.4 KB
  auto Bs = smem;
  int tid = threadIdx.x;
  int w = tid >> 6, lane = tid & 63, c = lane & 15, g = lane >> 4;
  int arow[4], acol[4];
#pragma unroll
  for (int i = 0; i < 4; i++) {
    int chunk = tid + 256 * i;
    arow[i] = chunk >> 3;
    acol[i] = (chunk & 7) * 8;
  }
  // A-fragment token rows for this thread (rows w*32+c and w*32+16+c of tile)
  int r1 = w * 32 + c, r2 = r1 + 16;
  long tokf0, tokf1;
  {
    int mr1 = m0 + r1, mr2 = m0 + r2;
    if constexpr (MODE == 2) {
      tokf0 = (mr1 < cnt) ? (long)(tl[mr1] & 0xFFFF) : -1;
      tokf1 = (mr2 < cnt) ? (long)(tl[mr2] & 0xFFFF) : -1;
    } else if constexpr (MODE == 3) {
      tokf0 = (mr1 < cnt) ? (long)(base + mr1) : -1;
      tokf1 = (mr2 < cnt) ? (long)(base + mr2) : -1;
    } else {
      tokf0 = mr1; tokf1 = mr2;
    }
  }
  f32x4 acc[2][8];
#pragma unroll
  for (int m = 0; m < 2; m++)
#pragma unroll
    for (int n = 0; n < 8; n++) { acc[m][n][0] = 0.f; acc[m][n][1] = 0.f; acc[m][n][2] = 0.f; acc[m][n][3] = 0.f; }

  bf16x8 rb[4];
  bf16x8 af0a = {}, af0b = {}, af1a = {}, af1b = {};
  int nk = K >> 6;
  // prologue loads (k0 = 0)
#pragma unroll
  for (int i = 0; i < 4; i++)
    rb[i] = *(const bf16x8*)&Wt[(size_t)(n0 + arow[i]) * K + acol[i]];
  if (tokf0 >= 0) {
    af0a = *(const bf16x8*)&Abf[(size_t)tokf0 * K + g * 8];
    af0b = *(const bf16x8*)&Abf[(size_t)tokf0 * K + 32 + g * 8];
  }
  if (tokf1 >= 0) {
    af1a = *(const bf16x8*)&Abf[(size_t)tokf1 * K + g * 8];
    af1b = *(const bf16x8*)&Abf[(size_t)tokf1 * K + 32 + g * 8];
  }
  for (int kt = 0; kt < nk; kt++) {
#pragma unroll
    for (int i = 0; i < 4; i++)
      *(bf16x8*)&Bs[arow[i]][acol[i]] = rb[i];
    __syncthreads();
    int k0 = (kt + 1) << 6;
    if (kt + 1 < nk) {      // B prefetch flies under the MFMA phase
#pragma unroll
      for (int i = 0; i < 4; i++)
        rb[i] = *(const bf16x8*)&Wt[(size_t)(n0 + arow[i]) * K + k0 + acol[i]];
    }
    // MFMA phase: A from registers, B from LDS
#pragma unroll
    for (int n = 0; n < 8; n++) {
      bf16x8 b0 = *(const bf16x8*)&Bs[n * 16 + c][g * 8];
      acc[0][n] = __builtin_amdgcn_mfma_f32_16x16x32_bf16(af0a, b0, acc[0][n], 0, 0, 0);
      acc[1][n] = __builtin_amdgcn_mfma_f32_16x16x32_bf16(af1a, b0, acc[1][n], 0, 0, 0);
    }
#pragma unroll
    for (int n = 0; n < 8; n++) {
      bf16x8 b1 = *(const bf16x8*)&Bs[n * 16 + c][32 + g * 8];
      acc[0][n] = __builtin_amdgcn_mfma_f32_16x16x32_bf16(af0b, b1, acc[0][n], 0, 0, 0);
      acc[1][n] = __builtin_amdgcn_mfma_f32_16x16x32_bf16(af1b, b1, acc[1][n], 0, 0, 0);
    }
    if (kt + 1 < nk) {      // A-fragment loads for kt+1, issued post-MFMA
      if (tokf0 >= 0) {
        af0a = *(const bf16x8*)&Abf[(size_t)tokf0 * K + k0 + g * 8];
        af0b = *(const bf16x8*)&Abf[(size_t)tokf0 * K + k0 + 32 + g * 8];
      }
      if (tokf1 >= 0) {
        af1a = *(const bf16x8*)&Abf[(size_t)tokf1 * K + k0 + g * 8];
        af1b = *(const bf16x8*)&Abf[(size_t)tokf1 * K + k0 + 32 + g * 8];
      }
    }
    __syncthreads();
  }
  if constexpr (MODE == 1) {
#pragma unroll
    for (int m = 0; m < 2; m++) {
      int row = w * 32 + m * 16 + 4 * g;
#pragma unroll
      for (int n = 0; n < 8; n++) {
        int col = n0 + n * 16 + c;
        float bv = bias[col];
#pragma unroll
        for (int r = 0; r < 4; r++)
          Cf[(size_t)(m0 + row + r) * N + col] += acc[m][n][r] + bv;
      }
    }
  } else if constexpr (MODE == 0) {
    // Half-tile LDS epilogue: [64][130] = 16.6 KB reuses the Bs region.
    __bf16* Ct = &smem[0][0];
    const int CSTR = 130;
    int which = n0 / 384;
    int rem0 = n0 - which * 384;
    int b0 = m0 >> 10, sbase = m0 & 1023;
    for (int h = 0; h < 2; h++) {
      __syncthreads();
      if ((w >> 1) == h) {
        int wl = w & 1;
#pragma unroll
        for (int m = 0; m < 2; m++) {
          int rowl = wl * 32 + m * 16 + 4 * g;
#pragma unroll
          for (int n = 0; n < 8; n++) {
            int col = n * 16 + c;
            float bv = bias[n0 + col];
#pragma unroll
            for (int r = 0; r < 4; r++) {
              float v = acc[m][n][r] + bv;
              if (which == 0) v *= 0.20823510262f;   // 1/sqrt(dh) * log2(e)
              Ct[(rowl + r) * CSTR + col] = (__bf16)v;
            }
          }
        }
      }
      __syncthreads();
      if (which < 2) {
        __bf16* dstbuf = (which == 0) ? pQ : pK;
#pragma unroll
        for (int it = 0; it < 2; it++) {
          int ch = it * 256 + tid;
          int rowl = ch >> 3, seg = ch & 7;
          int rem = rem0 + seg * 16;
          int hd = rem / 48, d = rem - hd * 48;
          size_t bh = (size_t)(b0 * 8 + hd);
          __bf16* dst = &dstbuf[(bh * 1024 + sbase + h * 64 + rowl) * 48 + d];
          const __bf16* srcl = &Ct[rowl * CSTR + seg * 16];
          *(bf16x8*)&dst[0] = *(const bf16x8*)&srcl[0];
          *(bf16x8*)&dst[8] = *(const bf16x8*)&srcl[8];
        }
      } else {
        if ((tid & 1) == h) {
          int col = tid >> 1;
          int rem = rem0 + col;
          int hd = rem / 48, d = rem - hd * 48;
          size_t bh = (size_t)(b0 * 8 + hd);
          __bf16* dst = &pV[(bh * 48 + d) * 1024 + sbase + h * 64];
          const __bf16* srcc = &Ct[col];
#pragma unroll
          for (int i8 = 0; i8 < 8; i8++) {
            bf16x8 vv;
#pragma unroll
            for (int j = 0; j < 8; j++) vv[j] = srcc[(i8 * 8 + j) * CSTR];
            *(bf16x8*)&dst[i8 * 8] = vv;
          }
        }
      }
    }
  } else {
    // MODE 2/3: half-tile LDS epilogue
    __bf16* Ct = &smem[0][0];
    const int CSTR = 130;
    float rowg[2][4];
    if constexpr (MODE == 3) {
#pragma unroll
      for (int m = 0; m < 2; m++)
#pragma unroll
        for (int r = 0; r < 4; r++) {
          int row = m0 + w * 32 + m * 16 + 4 * g + r;
          rowg[m][r] = (row < cnt) ? gate_list[e * TOKENS + row] : 0.f;
        }
    }
    for (int h = 0; h < 2; h++) {
      __syncthreads();
      if ((w >> 1) == h) {
        int wl = w & 1;
#pragma unroll
        for (int m = 0; m < 2; m++) {
          int rowl = wl * 32 + m * 16 + 4 * g;
#pragma unroll
          for (int n = 0; n < 8; n++) {
            int col = n * 16 + c;
            float bv = bias[n0 + col];
#pragma unroll
            for (int r = 0; r < 4; r++) {
              float v = acc[m][n][r] + bv;
              if constexpr (MODE == 2) v = fmaxf(v, 0.f);
              else v *= rowg[m][r];
              Ct[(rowl + r) * CSTR + col] = (__bf16)v;
            }
          }
        }
      }
      __syncthreads();
      int rowl = tid >> 2, q = tid & 3;
      int mr = m0 + h * 64 + rowl;
      if (mr < cnt) {
        const __bf16* srcl = &Ct[rowl * CSTR + q * 32];
        __bf16* dst;
        if constexpr (MODE == 2) {
          dst = &Cb[(size_t)(base + mr) * N + n0 + q * 32];
        } else {
          int entry = tl[mr];
          int t = entry & 0xFFFF, a = entry >> 16;
          dst = &Cb[((size_t)a * TOKENS + t) * DMODEL + n0 + q * 32];
        }
#pragma unroll
        for (int i = 0; i < 4; i++) *(bf16x8*)&dst[i * 8] = *(const bf16x8*)&srcl[i * 8];
      }
    }
  }
}

// combine: h += ab[0] + ab[1]   (final layer only; earlier layers use lncomb)
__global__ __launch_bounds__(256) void combine_kernel(float* __restrict__ h,
    const __bf16* __restrict__ ab) {
  size_t i = ((size_t)blockIdx.x * 256 + threadIdx.x) * 8;
  bf16x8 a0 = *(const bf16x8*)&ab[i];
  bf16x8 a1 = *(const bf16x8*)&ab[(size_t)TOKENS * DMODEL + i];
  float* hp = h + i;
#pragma unroll
  for (int j = 0; j < 8; j++) hp[j] += (float)a0[j] + (float)a1[j];
}

// ---------------- bf16 MFMA flash attention: 2 q-tiles per wave ----------------
__global__ __launch_bounds__(256, 4) void attn_kernel(const __bf16* __restrict__ Qh,
    const __bf16* __restrict__ Kh, const __bf16* __restrict__ VTh,
    __bf16* __restrict__ ao) {
  __shared__ __align__(16) __bf16 Ks[64][72];   // cols 48..63 zeroed (pad K-dim)
  __shared__ __align__(16) __bf16 Vt[48][72];
  __shared__ __align__(16) __bf16 Ps[4][2][16][72];
  int bh = blockIdx.x;
  int q0 = blockIdx.y * 128;
  int tid = threadIdx.x;
  int w = tid >> 6, lane = tid & 63, c = lane & 15, g = lane >> 4;

  for (int i = tid; i < 192; i += 256) {
    int row = i / 3, seg = i - row * 3;
    bf16x8 z = {};
    *(bf16x8*)&Ks[row][48 + seg * 8] = z;
  }

  const __bf16* qrowA = Qh + ((size_t)bh * 1024 + q0 + w * 16 + c) * 48;
  const __bf16* qrowB = qrowA + 64 * 48;
  bf16x8 qb0a = *(const bf16x8*)&qrowA[g * 8];
  bf16x8 qb0b = *(const bf16x8*)&qrowB[g * 8];
  bf16x8 qb1a = {}, qb1b = {};
  if (g < 2) {
    qb1a = *(const bf16x8*)&qrowA[32 + g * 8];
    qb1b = *(const bf16x8*)&qrowB[32 + g * 8];
  }

  const __bf16* kb = Kh + (size_t)bh * 1024 * 48;
  const __bf16* vb = VTh + (size_t)bh * 48 * 1024;

  int r0 = tid / 6, p0 = tid - r0 * 6;
  __bf16* dst0 = &Ks[r0][p0 * 8];
  int off0 = r0 * 48 + p0 * 8;
  int e1 = tid + 256;
  __bf16* dst1; int off1; bool v1;
  if (e1 < 384) { int r = e1 / 6, p = e1 - r * 6; dst1 = &Ks[r][p * 8]; off1 = r * 48 + p * 8; v1 = false; }
  else          { int i = e1 - 384; int d = i >> 3, p = i & 7; dst1 = &Vt[d][p * 8]; off1 = d * 1024 + p * 8; v1 = true; }
  int i2 = tid + 512 - 384;
  int d2 = i2 >> 3, p2 = i2 & 7;
  __bf16* dst2 = &Vt[d2][p2 * 8];
  int off2 = d2 * 1024 + p2 * 8;

  f32x4 accA[3] = {}, accB[3] = {};
  f32x4 laccA = {}, laccB = {};
  bf16x8 ones;
#pragma unroll
  for (int j = 0; j < 8; j++) ones[j] = (__bf16)1.0f;

  for (int kt = 0; kt < 16; kt++) {
    __syncthreads();
    const __bf16* kbt = kb + (size_t)kt * 3072;
    const __bf16* vbt = vb + kt * 64;
    *(bf16x8*)dst0 = *(const bf16x8*)(kbt + off0);
    *(bf16x8*)dst1 = *(const bf16x8*)((v1 ? vbt : kbt) + off1);
    *(bf16x8*)dst2 = *(const bf16x8*)(vbt + off2);
    __syncthreads();

#pragma unroll
    for (int f = 0; f < 4; f++) {
      bf16x8 ka0 = *(const bf16x8*)&Ks[f * 16 + c][g * 8];
      bf16x8 ka1 = *(const bf16x8*)&Ks[f * 16 + c][32 + g * 8];
      f32x4 za = {}, zb = {};
      za = __builtin_amdgcn_mfma_f32_16x16x32_bf16(ka0, qb0a, za, 0, 0, 0);
      f32x4 sa = __builtin_amdgcn_mfma_f32_16x16x32_bf16(ka1, qb1a, za, 0, 0, 0);
      zb = __builtin_amdgcn_mfma_f32_16x16x32_bf16(ka0, qb0b, zb, 0, 0, 0);
      f32x4 sb = __builtin_amdgcn_mfma_f32_16x16x32_bf16(ka1, qb1b, zb, 0, 0, 0);
      bf16x4 pka = { (__bf16)__builtin_amdgcn_exp2f(sa[0]), (__bf16)__builtin_amdgcn_exp2f(sa[1]),
                     (__bf16)__builtin_amdgcn_exp2f(sa[2]), (__bf16)__builtin_amdgcn_exp2f(sa[3]) };
      bf16x4 pkb = { (__bf16)__builtin_amdgcn_exp2f(sb[0]), (__bf16)__builtin_amdgcn_exp2f(sb[1]),
                     (__bf16)__builtin_amdgcn_exp2f(sb[2]), (__bf16)__builtin_amdgcn_exp2f(sb[3]) };
      *(bf16x4*)&Ps[w][0][c][f * 16 + 4 * g] = pka;
      *(bf16x4*)&Ps[w][1][c][f * 16 + 4 * g] = pkb;
    }
    bf16x8 pa0a = *(const bf16x8*)&Ps[w][0][c][g * 8];
    bf16x8 pa1a = *(const bf16x8*)&Ps[w][0][c][32 + g * 8];
    bf16x8 pa0b = *(const bf16x8*)&Ps[w][1][c][g * 8];
    bf16x8 pa1b = *(const bf16x8*)&Ps[w][1][c][32 + g * 8];
#pragma unroll
    for (int t = 0; t < 3; t++) {
      bf16x8 vb0 = *(const bf16x8*)&Vt[t * 16 + c][g * 8];
      bf16x8 vb1 = *(const bf16x8*)&Vt[t * 16 + c][32 + g * 8];
      accA[t] = __builtin_amdgcn_mfma_f32_16x16x32_bf16(pa0a, vb0, accA[t], 0, 0, 0);
      accA[t] = __builtin_amdgcn_mfma_f32_16x16x32_bf16(pa1a, vb1, accA[t], 0, 0, 0);
      accB[t] = __builtin_amdgcn_mfma_f32_16x16x32_bf16(pa0b, vb0, accB[t], 0, 0, 0);
      accB[t] = __builtin_amdgcn_mfma_f32_16x16x32_bf16(pa1b, vb1, accB[t], 0, 0, 0);
    }
    laccA = __builtin_amdgcn_mfma_f32_16x16x32_bf16(pa0a, ones, laccA, 0, 0, 0);
    laccA = __builtin_amdgcn_mfma_f32_16x16x32_bf16(pa1a, ones, laccA, 0, 0, 0);
    laccB = __builtin_amdgcn_mfma_f32_16x16x32_bf16(pa0b, ones, laccB, 0, 0, 0);
    laccB = __builtin_amdgcn_mfma_f32_16x16x32_bf16(pa1b, ones, laccB, 0, 0, 0);
  }
  float linvA[4], linvB[4];
#pragma unroll
  for (int r = 0; r < 4; r++) { linvA[r] = 1.f / laccA[r]; linvB[r] = 1.f / laccB[r]; }
  int b = bh >> 3, hh = bh & 7;
#pragma unroll
  for (int t = 0; t < 3; t++)
#pragma unroll
    for (int r = 0; r < 4; r++) {
      size_t rowA = (size_t)(b * SEQ + q0 + w * 16 + 4 * g + r);
      ao[rowA * DMODEL + hh * 48 + t * 16 + c] = (__bf16)(accA[t][r] * linvA[r]);
      ao[(rowA + 64) * DMODEL + hh * 48 + t * 16 + c] = (__bf16)(accB[t][r] * linvB[r]);
    }
}

// ---------------- gating: block = 32 tokens (512 blocks), block-aggregated atomics ----
__global__ __launch_bounds__(256) void gate_kernel(const __bf16* __restrict__ xnb,
    const float* __restrict__ gw, int* __restrict__ counts, float* __restrict__ sum_probs,
    int* __restrict__ tok_list, float* __restrict__ gate_list) {
  __shared__ float Gs[NEXP][DMODEL];
  __shared__ float simp[NEXP];
  __shared__ int hist[NEXP], basep[NEXP];
  __shared__ unsigned char tokE[32][2];
  __shared__ float tokG[32][2];
  __shared__ short rankS[32][2];
  int tid = threadIdx.x;
  for (int i = tid; i < DMODEL * NEXP; i += 256) {
    int d = i >> 3, e2 = i & 7;
    Gs[e2][d] = gw[i];
  }
  if (tid < NEXP) { simp[tid] = 0.f; hist[tid] = 0; }
  __syncthreads();
  int w = tid >> 6, lane = tid & 63;
  int tbase = blockIdx.x * 32 + w * 8;
  float impacc[NEXP] = {};
  for (int tt = 0; tt < 8; tt++) {
    int t = tbase + tt;
    float p[NEXP] = {};
#pragma unroll
    for (int j = 0; j < 6; j++) {
      int d = lane + 64 * j;
      float xv = (float)xnb[(size_t)t * DMODEL + d];
#pragma unroll
      for (int e2 = 0; e2 < NEXP; e2++) p[e2] += xv * Gs[e2][d];
    }
#pragma unroll
    for (int off = 32; off; off >>= 1)
#pragma unroll
      for (int e2 = 0; e2 < NEXP; e2++) p[e2] += __shfl_xor(p[e2], off);
    float mx = p[0];
#pragma unroll
    for (int e2 = 1; e2 < NEXP; e2++) mx = fmaxf(mx, p[e2]);
    float s = 0.f;
#pragma unroll
    for (int e2 = 0; e2 < NEXP; e2++) { p[e2] = __expf(p[e2] - mx); s += p[e2]; }
    float inv = 1.f / s;
#pragma unroll
    for (int e2 = 0; e2 < NEXP; e2++) { p[e2] *= inv; impacc[e2] += p[e2]; }
    int i0 = 0; float v0 = p[0];
#pragma unroll
    for (int e2 = 1; e2 < NEXP; e2++) if (p[e2] > v0) { v0 = p[e2]; i0 = e2; }
    int i1 = -1; float v1 = -INFINITY;
#pragma unroll
    for (int e2 = 0; e2 < NEXP; e2++) if (e2 != i0 && p[e2] > v1) { v1 = p[e2]; i1 = e2; }
    if (lane == 0) {
      float gsum = v0 + v1;
      int r0 = atomicAdd(&hist[i0], 1);
      int r1 = atomicAdd(&hist[i1], 1);
      int sl = w * 8 + tt;
      tokE[sl][0] = (unsigned char)i0; tokE[sl][1] = (unsigned char)i1;
      tokG[sl][0] = v0 / gsum;         tokG[sl][1] = v1 / gsum;
      rankS[sl][0] = (short)r0;        rankS[sl][1] = (short)r1;
    }
  }
  if (lane == 0)
#pragma unroll
    for (int e2 = 0; e2 < NEXP; e2++) atomicAdd(&simp[e2], impacc[e2]);
  __syncthreads();
  if (tid < NEXP) {
    basep[tid] = atomicAdd(&counts[tid], hist[tid]);
    atomicAdd(&sum_probs[tid], simp[tid]);
  }
  __syncthreads();
  int t0 = blockIdx.x * 32;
  if (tid < 64) {
    int sl = tid >> 1, a = tid & 1;
    int e2 = tokE[sl][a];
    int pos = basep[e2] + rankS[sl][a];
    tok_list[e2 * TOKENS + pos] = (t0 + sl) | (a << 16);
    gate_list[e2 * TOKENS + pos] = tokG[sl][a];
  }
}

// ---------------- attention-pool head, split for parallelism ----------------
__global__ __launch_bounds__(256) void head1_kernel(const float* __restrict__ h,
    const float* __restrict__ att_w, const float* __restrict__ att_b,
    float* __restrict__ logits) {
  int tid = threadIdx.x;
  int w = tid >> 6, lane = tid & 63;
  float4 aw0 = *(const float4*)&att_w[lane * 4];
  float2 aw1 = *(const float2*)&att_w[256 + lane * 2];
  float ab = att_b[0];
  for (int i = w; i < 32; i += 4) {
    int t = blockIdx.x * 32 + i;
    const float* hr = h + (size_t)t * DMODEL;
    float4 v4 = *(const float4*)&hr[lane * 4];
    float2 v2 = *(const float2*)&hr[256 + lane * 2];
    float dot = v4.x * aw0.x + v4.y * aw0.y + v4.z * aw0.z + v4.w * aw0.w
              + v2.x * aw1.x + v2.y * aw1.y;
#pragma unroll
    for (int off = 32; off; off >>= 1) dot += __shfl_xor(dot, off);
    if (lane == 0) logits[t] = dot + ab;
  }
}

__global__ __launch_bounds__(256) void head2_kernel(float* __restrict__ logits) {
  int b = blockIdx.x, tid = threadIdx.x;
  int w = tid >> 6, lane = tid & 63;
  float* lb = logits + b * SEQ;
  __shared__ float red[4];
  float lv[4];
  float mx = -INFINITY;
#pragma unroll
  for (int i = 0; i < 4; i++) { lv[i] = lb[tid + 256 * i]; mx = fmaxf(mx, lv[i]); }
#pragma unroll
  for (int off = 32; off; off >>= 1) mx = fmaxf(mx, __shfl_xor(mx, off));
  if (lane == 0) red[w] = mx;
  __syncthreads();
  mx = fmaxf(fmaxf(red[0], red[1]), fmaxf(red[2], red[3]));
  __syncthreads();
  float s = 0.f;
#pragma unroll
  for (int i = 0; i < 4; i++) { lv[i] = __expf(lv[i] - mx); s += lv[i]; }
#pragma unroll
  for (int off = 32; off; off >>= 1) s += __shfl_xor(s, off);
  if (lane == 0) red[w] = s;
  __syncthreads();
  float inv = 1.f / (red[0] + red[1] + red[2] + red[3]);
#pragma unroll
  for (int i = 0; i < 4; i++) lb[tid + 256 * i] = lv[i] * inv;
}

__global__ __launch_bounds__(256) void head3a_kernel(const float* __restrict__ h,
    const float* __restrict__ wnorm, float* __restrict__ partial) {
  int b = blockIdx.x, dc = blockIdx.y, sc = blockIdx.z;
  int tid = threadIdx.x;
  int d = tid & 63, sg = tid >> 6;
  const float* hb = h + (size_t)b * SEQ * DMODEL + dc * 64 + d;
  const float* wb = wnorm + b * SEQ + sc * 64;
  float acc = 0.f;
  int s0 = sc * 64 + sg * 16;
#pragma unroll
  for (int i = 0; i < 16; i++)
    acc += wb[sg * 16 + i] * hb[(size_t)(s0 + i) * DMODEL];
  __shared__ float red[256];
  red[tid] = acc;
  __syncthreads();
  if (sg == 0)
    partial[(((size_t)b * 6 + dc) * 16 + sc) * 64 + d] =
        red[d] + red[64 + d] + red[128 + d] + red[192 + d];
}

__global__ void head3b_kernel(const float* __restrict__ partial,
    const float* __restrict__ head_w, float* __restrict__ part) {
  int b = blockIdx.x, dc = blockIdx.y;
  int d = threadIdx.x;
  const float* pp = partial + (((size_t)b * 6 + dc) * 16) * 64 + d;
  float pooled = 0.f;
#pragma unroll
  for (int sc = 0; sc < 16; sc++) pooled += pp[sc * 64];
  float pd = pooled * head_w[dc * 64 + d];
#pragma unroll
  for (int off = 32; off; off >>= 1) pd += __shfl_xor(pd, off);
  if (d == 0) part[b * 6 + dc] = pd;
}

__global__ void head4_kernel(const float* __restrict__ part,
                             const float* __restrict__ head_b, float* __restrict__ out) {
  int b = threadIdx.x;
  if (b < 16) {
    float s = head_b[0];
#pragma unroll
    for (int dc = 0; dc < 6; dc++) s += part[b * 6 + dc];
    out[b] = s;
  }
}

// ---------------- launch ----------------
extern "C" void kernel_launch(void* const* d_in, const int* in_sizes, int n_in,
                              void* d_out, int out_size, void* d_ws, size_t ws_size,
                              hipStream_t stream) {
  (void)in_sizes; (void)n_in; (void)out_size; (void)ws_size;
  const float* x      = (const float*)d_in[0];
  const float* proj_w = (const float*)d_in[1];
  const float* proj_b = (const float*)d_in[2];
  const float* qkv_w  = (const float*)d_in[3];
  const float* qkv_b  = (const float*)d_in[4];
  const float* out_w  = (const float*)d_in[5];
  const float* out_b  = (const float*)d_in[6];
  const float* n1_s   = (const float*)d_in[7];
  const float* n1_b   = (const float*)d_in[8];
  const float* n2_s   = (const float*)d_in[9];
  const float* n2_b   = (const float*)d_in[10];
  const float* gate_w = (const float*)d_in[11];
  const float* e_w1   = (const float*)d_in[12];
  const float* e_b1   = (const float*)d_in[13];
  const float* e_w2   = (const float*)d_in[14];
  const float* e_b2   = (const float*)d_in[15];
  const float* att_w  = (const float*)d_in[16];
  const float* att_b  = (const float*)d_in[17];
  const float* head_w = (const float*)d_in[18];
  const float* head_b = (const float*)d_in[19];
  float* out = (float*)d_out;

  char* wsb = (char*)d_ws;
  float*  h    = (float*)(wsb);
  __bf16* xnb  = (__bf16*)(wsb + 25165824);
  __bf16* aob  = (__bf16*)(wsb + 37748736);
  __bf16* ab   = (__bf16*)(wsb + 25165824);        // [2][16384][384] aliases xnb+aob
  __bf16* uni  = (__bf16*)(wsb + 50331648);        // qkv-major region / a1b
  __bf16* Qh   = uni;                              // [128][1024][48]
  __bf16* Khd  = (__bf16*)(wsb + 62914560);
  __bf16* VTh  = (__bf16*)(wsb + 75497472);
  __bf16* qkvWt = (__bf16*)(wsb + 101449728);   // [3][1152][384]
  __bf16* outWt = (__bf16*)(wsb + 104103936);   // [3][384][384]
  __bf16* e1Wt  = (__bf16*)(wsb + 104988672);   // [3*8][768][384]
  __bf16* e2Wt  = (__bf16*)(wsb + 119144448);   // [3*8][384][768]
  char* sm = wsb + 133300224;
  int*   counts_all = (int*)(sm);                  // [3][8]
  float* sp_all     = (float*)(sm + 128);          // [3][8]
  int*   tok_list  = (int*)(sm + 256);
  float* gate_list = (float*)(sm + 256 + 524288);
  float* logits    = (float*)(sm + 1048832);
  float* part      = (float*)(sm + 1048832 + 65536);
  float* partial   = (float*)(sm + 1048832 + 131072);   // [16][6][16][64]

  convw_kernel<<<dim3(36, 12, 3), 256, 0, stream>>>(qkv_w, qkvWt, 384, 1152);
  convw_kernel<<<dim3(12, 12, 3), 256, 0, stream>>>(out_w, outWt, 384, 384);
  convw_kernel<<<dim3(24, 12, 24), 256, 0, stream>>>(e_w1, e1Wt, 384, 768);
  convw_kernel<<<dim3(12, 24, 24), 256, 0, stream>>>(e_w2, e2Wt, 768, 384);

  proj_kernel<<<TOKENS * DMODEL / 256, 256, 0, stream>>>(x, proj_w, proj_b, h);
  ln_kernel<<<TOKENS, 384, 0, stream>>>(h, xnb, n1_s, n1_b, nullptr, nullptr);

  for (int l = 0; l < NL; l++) {
    int*   counts = counts_all + l * NEXP;
    float* sp     = sp_all + l * NEXP;
    mgemm_kernel<0><<<dim3(9, 128), 256, 0, stream>>>(
        xnb, qkvWt + (size_t)l * 1152 * 384, qkv_b + l * 1152, nullptr, nullptr,
        Qh, Khd, VTh, nullptr, nullptr, nullptr, 1152, 384);
    attn_kernel<<<dim3(128, 8), 256, 0, stream>>>(Qh, Khd, VTh, aob);
    mgemm_kernel<1><<<dim3(3, 128), 256, 0, stream>>>(
        aob, outWt + (size_t)l * 384 * 384, out_b + l * 384, h, nullptr,
        nullptr, nullptr, nullptr, nullptr, nullptr, nullptr, 384, 384);
    // n2 LayerNorm also zeroes this layer's counts/sum_probs (block 0)
    ln_kernel<<<TOKENS, 384, 0, stream>>>(h, xnb, n2_s + l * DMODEL, n2_b + l * DMODEL,
                                          counts, sp);
    gate_kernel<<<512, 256, 0, stream>>>(xnb, gate_w + (size_t)l * DMODEL * NEXP,
                                         counts, sp, tok_list, gate_list);
    mgemm_kernel<2><<<dim3(6, 128, 8), 256, 0, stream>>>(
        xnb, e1Wt + (size_t)l * 8 * 768 * 384, e_b1 + l * 8 * FFDIM, nullptr, uni,
        nullptr, nullptr, nullptr, counts, tok_list, nullptr, 768, 384);
    mgemm_kernel<3><<<dim3(3, 128, 8), 256, 0, stream>>>(
        uni, e2Wt + (size_t)l * 8 * 384 * 768, e_b2 + l * 8 * DMODEL, nullptr, ab,
        nullptr, nullptr, nullptr, counts, tok_list, gate_list, 384, 768);
    if (l + 1 < NL) {
      lncomb_kernel<<<TOKENS, 384, 0, stream>>>(h, ab, xnb,
          n1_s + (l + 1) * DMODEL, n1_b + (l + 1) * DMODEL);
    } else {
      combine_kernel<<<TOKENS * DMODEL / (256 * 8), 256, 0, stream>>>(h, ab);
    }
  }

  head1_kernel<<<512, 256, 0, stream>>>(h, att_w, att_b, logits);
  head2_kernel<<<16, 256, 0, stream>>>(logits);
  head3a_kernel<<<dim3(16, 6, 16), 256, 0, stream>>>(h, logits, partial);
  head3b_kernel<<<dim3(16, 6), 64, 0, stream>>>(partial, head_w, part);
  head4_kernel<<<1, 64, 0, stream>>>(part, head_b, out);
  finalize_kernel<<<1, 1, 0, stream>>>(counts_all, sp_all, out);
}

// Round 30
// 866.947 us; speedup vs baseline: 1.0228x; 1.0228x over previous
//
#include <hip/hip_runtime.h>
#include <hip/hip_bf16.h>
#include <math.h>

// RULPredictionModel: B=16 S=1024 D=384 H=8 DH=48 L=3 E=8 FF=768 TOP_K=2
#define TOKENS 16384
#define DMODEL 384
#define SEQ 1024
#define NHEAD 8
#define DHEAD 48
#define NEXP 8
#define FFDIM 768
#define NL 3

typedef __bf16 bf16x8 __attribute__((ext_vector_type(8)));
typedef __bf16 bf16x4 __attribute__((ext_vector_type(4)));
typedef float f32x4 __attribute__((ext_vector_type(4)));

// ---------------- tiny kernels ----------------
// finalize: total_moe from per-layer counts/sum_probs
__global__ void finalize_kernel(const int* __restrict__ counts_all,
                                const float* __restrict__ sp_all, float* __restrict__ out) {
  float tm = 0.f;
  for (int l = 0; l < NL; l++) {
    float t = 0.f;
    for (int e = 0; e < NEXP; e++)
      t += sp_all[l * NEXP + e] * (float)counts_all[l * NEXP + e];
    tm += (float)NEXP * t / ((float)TOKENS * (float)TOKENS);
  }
  out[16] = tm;
}

__global__ __launch_bounds__(256) void proj_kernel(const float* __restrict__ x,
    const float* __restrict__ pw, const float* __restrict__ pb, float* __restrict__ h) {
  int i = blockIdx.x * 256 + threadIdx.x;
  int t = i / DMODEL;
  int d = i - t * DMODEL;
  h[i] = x[t] * pw[d] + pb[d];
}

// weight transpose + cast: src fp32 [K][N] (batched) -> dst bf16 [N][K]
__global__ __launch_bounds__(256) void convw_kernel(const float* __restrict__ src,
    __bf16* __restrict__ dst, int K, int N) {
  __shared__ float t[32][33];
  size_t boff = (size_t)blockIdx.z * K * N;
  src += boff; dst += boff;
  int k0 = blockIdx.y * 32, n0 = blockIdx.x * 32;
  int tx = threadIdx.x & 31, ty = threadIdx.x >> 5;   // 32 x 8
#pragma unroll
  for (int i = 0; i < 32; i += 8) t[ty + i][tx] = src[(size_t)(k0 + ty + i) * N + n0 + tx];
  __syncthreads();
#pragma unroll
  for (int i = 0; i < 32; i += 8)
    dst[(size_t)(n0 + ty + i) * K + k0 + tx] = (__bf16)t[tx][ty + i];
}

// one block (384 threads) per row; bf16 output.
// If zc/zs non-null, block 0 zeroes that layer's counts/sum_probs slice
// (gate runs strictly after this kernel in stream order).
__global__ __launch_bounds__(384) void ln_kernel(const float* __restrict__ src,
    __bf16* __restrict__ dst, const float* __restrict__ gs, const float* __restrict__ gb,
    int* __restrict__ zc, float* __restrict__ zs) {
  int row = blockIdx.x, tid = threadIdx.x;
  if (zc && row == 0 && tid < NEXP) { zc[tid] = 0; zs[tid] = 0.f; }
  float v = src[(size_t)row * DMODEL + tid];
  float sum = v, sq = v * v;
#pragma unroll
  for (int off = 32; off; off >>= 1) { sum += __shfl_xor(sum, off); sq += __shfl_xor(sq, off); }
  __shared__ float rs[6], rq[6];
  __shared__ float smean, sinv;
  int wid = tid >> 6;
  if ((tid & 63) == 0) { rs[wid] = sum; rq[wid] = sq; }
  __syncthreads();
  if (tid == 0) {
    float S = 0.f, Q = 0.f;
    for (int w = 0; w < 6; w++) { S += rs[w]; Q += rq[w]; }
    float mean = S / (float)DMODEL;
    float var = Q / (float)DMODEL - mean * mean;
    smean = mean; sinv = rsqrtf(var + 1e-5f);
  }
  __syncthreads();
  dst[(size_t)row * DMODEL + tid] = (__bf16)((v - smean) * sinv * gs[tid] + gb[tid]);
}

// fused combine + layernorm: h += ab0+ab1; dst = LN(h)  (one h pass saved)
__global__ __launch_bounds__(384) void lncomb_kernel(float* __restrict__ h,
    const __bf16* __restrict__ ab, __bf16* __restrict__ dst,
    const float* __restrict__ gs, const float* __restrict__ gb) {
  int row = blockIdx.x, tid = threadIdx.x;
  size_t idx = (size_t)row * DMODEL + tid;
  float v = h[idx] + (float)ab[idx] + (float)ab[(size_t)TOKENS * DMODEL + idx];
  h[idx] = v;
  float sum = v, sq = v * v;
#pragma unroll
  for (int off = 32; off; off >>= 1) { sum += __shfl_xor(sum, off); sq += __shfl_xor(sq, off); }
  __shared__ float rs[6], rq[6];
  __shared__ float smean, sinv;
  int wid = tid >> 6;
  if ((tid & 63) == 0) { rs[wid] = sum; rq[wid] = sq; }
  __syncthreads();
  if (tid == 0) {
    float S = 0.f, Q = 0.f;
    for (int w = 0; w < 6; w++) { S += rs[w]; Q += rq[w]; }
    float mean = S / (float)DMODEL;
    float var = Q / (float)DMODEL - mean * mean;
    smean = mean; sinv = rsqrtf(var + 1e-5f);
  }
  __syncthreads();
  dst[idx] = (__bf16)((v - smean) * sinv * gs[tid] + gb[tid]);
}

// ---------------- bf16 MFMA GEMM: C = A @ Wt^T + bias, tile 128x128x64 ----------------
// A-path LDS bypass (r28) + PER-MODE LDS footprint (r29 lesson):
//   MODE 0: [128][130] = 33.3 KB, full-tile single-pass epilogue (r28 form).
//   MODE 1: [128][72]  = 18.4 KB (no LDS epilogue) -> 6 blocks/CU.
//   MODE 2/3: [128][72] = 18.4 KB, half-tile 2-phase epilogue -> 6 blocks/CU.
// MODE 0: qkv   (A=xnb, writes head-major (scale*log2e)*Qh / Kh + transposed VTh)
// MODE 1: out   (A=aob,  Cf += acc+bias)   [residual]
// MODE 2: moe1  (A=gather(xnb) via tok_list&0xFFFF, relu, out bf16 a1)
// MODE 3: moe2  (A=a1b rows base+m, gated; out bf16 ab[a][t])
template<int MODE>
__global__ __launch_bounds__(256) void mgemm_kernel(
    const __bf16* __restrict__ Abf, const __bf16* __restrict__ Wt,
    const float* __restrict__ bias, float* __restrict__ Cf, __bf16* __restrict__ Cb,
    __bf16* __restrict__ pQ, __bf16* __restrict__ pK, __bf16* __restrict__ pV,
    const int* __restrict__ counts,
    const int* __restrict__ tok_list, const float* __restrict__ gate_list,
    int N, int K) {
  int e = 0, cnt = 0, base = 0;
  const int* tl = nullptr;
  int m0 = blockIdx.y * 128;
  int n0 = blockIdx.x * 128;
  if constexpr (MODE == 2 || MODE == 3) {
    e = blockIdx.z;
    cnt = counts[e];
    if (m0 >= cnt) return;
    for (int i = 0; i < NEXP; i++) {          // inline 64-padded prefix offset
      int ci = counts[i];
      if (i < e) base += (ci + 63) & ~63;
    }
    tl = tok_list + e * TOKENS;
    Wt += (size_t)e * N * K;
    bias += (size_t)e * N;
  }
  constexpr int SW = (MODE == 0) ? 130 : 72;
  __shared__ __align__(16) __bf16 smem[128][SW];
  auto Bs = reinterpret_cast<__bf16(*)[72]>(&smem[0][0]);
  int tid = threadIdx.x;
  int w = tid >> 6, lane = tid & 63, c = lane & 15, g = lane >> 4;
  int arow[4], acol[4];
#pragma unroll
  for (int i = 0; i < 4; i++) {
    int chunk = tid + 256 * i;
    arow[i] = chunk >> 3;
    acol[i] = (chunk & 7) * 8;
  }
  // A-fragment token rows for this thread (rows w*32+c and w*32+16+c of tile)
  int r1 = w * 32 + c, r2 = r1 + 16;
  long tokf0, tokf1;
  {
    int mr1 = m0 + r1, mr2 = m0 + r2;
    if constexpr (MODE == 2) {
      tokf0 = (mr1 < cnt) ? (long)(tl[mr1] & 0xFFFF) : -1;
      tokf1 = (mr2 < cnt) ? (long)(tl[mr2] & 0xFFFF) : -1;
    } else if constexpr (MODE == 3) {
      tokf0 = (mr1 < cnt) ? (long)(base + mr1) : -1;
      tokf1 = (mr2 < cnt) ? (long)(base + mr2) : -1;
    } else {
      tokf0 = mr1; tokf1 = mr2;
    }
  }
  f32x4 acc[2][8];
#pragma unroll
  for (int m = 0; m < 2; m++)
#pragma unroll
    for (int n = 0; n < 8; n++) { acc[m][n][0] = 0.f; acc[m][n][1] = 0.f; acc[m][n][2] = 0.f; acc[m][n][3] = 0.f; }

  bf16x8 rb[4];
  bf16x8 af0a = {}, af0b = {}, af1a = {}, af1b = {};
  int nk = K >> 6;
  // prologue loads (k0 = 0)
#pragma unroll
  for (int i = 0; i < 4; i++)
    rb[i] = *(const bf16x8*)&Wt[(size_t)(n0 + arow[i]) * K + acol[i]];
  if (tokf0 >= 0) {
    af0a = *(const bf16x8*)&Abf[(size_t)tokf0 * K + g * 8];
    af0b = *(const bf16x8*)&Abf[(size_t)tokf0 * K + 32 + g * 8];
  }
  if (tokf1 >= 0) {
    af1a = *(const bf16x8*)&Abf[(size_t)tokf1 * K + g * 8];
    af1b = *(const bf16x8*)&Abf[(size_t)tokf1 * K + 32 + g * 8];
  }
  for (int kt = 0; kt < nk; kt++) {
#pragma unroll
    for (int i = 0; i < 4; i++)
      *(bf16x8*)&Bs[arow[i]][acol[i]] = rb[i];
    __syncthreads();
    int k0 = (kt + 1) << 6;
    if (kt + 1 < nk) {      // B prefetch flies under the MFMA phase
#pragma unroll
      for (int i = 0; i < 4; i++)
        rb[i] = *(const bf16x8*)&Wt[(size_t)(n0 + arow[i]) * K + k0 + acol[i]];
    }
    // MFMA phase: A from registers, B from LDS
#pragma unroll
    for (int n = 0; n < 8; n++) {
      bf16x8 b0 = *(const bf16x8*)&Bs[n * 16 + c][g * 8];
      acc[0][n] = __builtin_amdgcn_mfma_f32_16x16x32_bf16(af0a, b0, acc[0][n], 0, 0, 0);
      acc[1][n] = __builtin_amdgcn_mfma_f32_16x16x32_bf16(af1a, b0, acc[1][n], 0, 0, 0);
    }
#pragma unroll
    for (int n = 0; n < 8; n++) {
      bf16x8 b1 = *(const bf16x8*)&Bs[n * 16 + c][32 + g * 8];
      acc[0][n] = __builtin_amdgcn_mfma_f32_16x16x32_bf16(af0b, b1, acc[0][n], 0, 0, 0);
      acc[1][n] = __builtin_amdgcn_mfma_f32_16x16x32_bf16(af1b, b1, acc[1][n], 0, 0, 0);
    }
    if (kt + 1 < nk) {      // A-fragment loads for kt+1, issued post-MFMA
      if (tokf0 >= 0) {
        af0a = *(const bf16x8*)&Abf[(size_t)tokf0 * K + k0 + g * 8];
        af0b = *(const bf16x8*)&Abf[(size_t)tokf0 * K + k0 + 32 + g * 8];
      }
      if (tokf1 >= 0) {
        af1a = *(const bf16x8*)&Abf[(size_t)tokf1 * K + k0 + g * 8];
        af1b = *(const bf16x8*)&Abf[(size_t)tokf1 * K + k0 + 32 + g * 8];
      }
    }
    __syncthreads();
  }
  if constexpr (MODE == 1) {
#pragma unroll
    for (int m = 0; m < 2; m++) {
      int row = w * 32 + m * 16 + 4 * g;
#pragma unroll
      for (int n = 0; n < 8; n++) {
        int col = n0 + n * 16 + c;
        float bv = bias[col];
#pragma unroll
        for (int r = 0; r < 4; r++)
          Cf[(size_t)(m0 + row + r) * N + col] += acc[m][n][r] + bv;
      }
    }
  } else if constexpr (MODE == 0) {
    // Full-tile LDS-coalesced epilogue (r28 form): [128][130]
    __bf16* Ct = &smem[0][0];
    const int CSTR = 130;
    int which = n0 / 384;
    int rem0 = n0 - which * 384;
#pragma unroll
    for (int m = 0; m < 2; m++) {
      int row = w * 32 + m * 16 + 4 * g;
#pragma unroll
      for (int n = 0; n < 8; n++) {
        int col = n * 16 + c;
        float bv = bias[n0 + col];
#pragma unroll
        for (int r = 0; r < 4; r++) {
          float v = acc[m][n][r] + bv;
          if (which == 0) v *= 0.20823510262f;   // 1/sqrt(dh) * log2(e)
          Ct[(row + r) * CSTR + col] = (__bf16)v;
        }
      }
    }
    __syncthreads();
    int b0 = m0 >> 10, sbase = m0 & 1023;
    if (which < 2) {
      __bf16* dstbuf = (which == 0) ? pQ : pK;
#pragma unroll
      for (int it = 0; it < 4; it++) {
        int ch = it * 256 + tid;
        int row = ch >> 3, seg = ch & 7;
        int rem = rem0 + seg * 16;
        int hd = rem / 48, d = rem - hd * 48;
        size_t bh = (size_t)(b0 * 8 + hd);
        __bf16* dst = &dstbuf[(bh * 1024 + sbase + row) * 48 + d];
        const __bf16* srcl = &Ct[row * CSTR + seg * 16];
        *(bf16x8*)&dst[0] = *(const bf16x8*)&srcl[0];
        *(bf16x8*)&dst[8] = *(const bf16x8*)&srcl[8];
      }
    } else {
      int col = tid >> 1, half = tid & 1;
      int rem = rem0 + col;
      int hd = rem / 48, d = rem - hd * 48;
      size_t bh = (size_t)(b0 * 8 + hd);
      __bf16* dst = &pV[(bh * 48 + d) * 1024 + sbase + half * 64];
      const __bf16* srcc = &Ct[(half * 64) * CSTR + col];
#pragma unroll
      for (int i8 = 0; i8 < 8; i8++) {
        bf16x8 vv;
#pragma unroll
        for (int j = 0; j < 8; j++) vv[j] = srcc[(i8 * 8 + j) * CSTR];
        *(bf16x8*)&dst[i8 * 8] = vv;
      }
    }
  } else {
    // MODE 2/3: half-tile 2-phase LDS epilogue (fits in [128][72] region)
    __bf16* Ct = &smem[0][0];
    const int CSTR = 130;
    float rowg[2][4];
    if constexpr (MODE == 3) {
#pragma unroll
      for (int m = 0; m < 2; m++)
#pragma unroll
        for (int r = 0; r < 4; r++) {
          int row = m0 + w * 32 + m * 16 + 4 * g + r;
          rowg[m][r] = (row < cnt) ? gate_list[e * TOKENS + row] : 0.f;
        }
    }
    for (int h = 0; h < 2; h++) {
      __syncthreads();
      if ((w >> 1) == h) {
        int wl = w & 1;
#pragma unroll
        for (int m = 0; m < 2; m++) {
          int rowl = wl * 32 + m * 16 + 4 * g;
#pragma unroll
          for (int n = 0; n < 8; n++) {
            int col = n * 16 + c;
            float bv = bias[n0 + col];
#pragma unroll
            for (int r = 0; r < 4; r++) {
              float v = acc[m][n][r] + bv;
              if constexpr (MODE == 2) v = fmaxf(v, 0.f);
              else v *= rowg[m][r];
              Ct[(rowl + r) * CSTR + col] = (__bf16)v;
            }
          }
        }
      }
      __syncthreads();
      int rowl = tid >> 2, q = tid & 3;
      int mr = m0 + h * 64 + rowl;
      if (mr < cnt) {
        const __bf16* srcl = &Ct[rowl * CSTR + q * 32];
        __bf16* dst;
        if constexpr (MODE == 2) {
          dst = &Cb[(size_t)(base + mr) * N + n0 + q * 32];
        } else {
          int entry = tl[mr];
          int t = entry & 0xFFFF, a = entry >> 16;
          dst = &Cb[((size_t)a * TOKENS + t) * DMODEL + n0 + q * 32];
        }
#pragma unroll
        for (int i = 0; i < 4; i++) *(bf16x8*)&dst[i * 8] = *(const bf16x8*)&srcl[i * 8];
      }
    }
  }
}

// combine: h += ab[0] + ab[1]   (final layer only; earlier layers use lncomb)
__global__ __launch_bounds__(256) void combine_kernel(float* __restrict__ h,
    const __bf16* __restrict__ ab) {
  size_t i = ((size_t)blockIdx.x * 256 + threadIdx.x) * 8;
  bf16x8 a0 = *(const bf16x8*)&ab[i];
  bf16x8 a1 = *(const bf16x8*)&ab[(size_t)TOKENS * DMODEL + i];
  float* hp = h + i;
#pragma unroll
  for (int j = 0; j < 8; j++) hp[j] += (float)a0[j] + (float)a1[j];
}

// ---------------- bf16 MFMA flash attention: 2 q-tiles per wave ----------------
__global__ __launch_bounds__(256, 4) void attn_kernel(const __bf16* __restrict__ Qh,
    const __bf16* __restrict__ Kh, const __bf16* __restrict__ VTh,
    __bf16* __restrict__ ao) {
  __shared__ __align__(16) __bf16 Ks[64][72];   // cols 48..63 zeroed (pad K-dim)
  __shared__ __align__(16) __bf16 Vt[48][72];
  __shared__ __align__(16) __bf16 Ps[4][2][16][72];
  int bh = blockIdx.x;
  int q0 = blockIdx.y * 128;
  int tid = threadIdx.x;
  int w = tid >> 6, lane = tid & 63, c = lane & 15, g = lane >> 4;

  for (int i = tid; i < 192; i += 256) {
    int row = i / 3, seg = i - row * 3;
    bf16x8 z = {};
    *(bf16x8*)&Ks[row][48 + seg * 8] = z;
  }

  const __bf16* qrowA = Qh + ((size_t)bh * 1024 + q0 + w * 16 + c) * 48;
  const __bf16* qrowB = qrowA + 64 * 48;
  bf16x8 qb0a = *(const bf16x8*)&qrowA[g * 8];
  bf16x8 qb0b = *(const bf16x8*)&qrowB[g * 8];
  bf16x8 qb1a = {}, qb1b = {};
  if (g < 2) {
    qb1a = *(const bf16x8*)&qrowA[32 + g * 8];
    qb1b = *(const bf16x8*)&qrowB[32 + g * 8];
  }

  const __bf16* kb = Kh + (size_t)bh * 1024 * 48;
  const __bf16* vb = VTh + (size_t)bh * 48 * 1024;

  int r0 = tid / 6, p0 = tid - r0 * 6;
  __bf16* dst0 = &Ks[r0][p0 * 8];
  int off0 = r0 * 48 + p0 * 8;
  int e1 = tid + 256;
  __bf16* dst1; int off1; bool v1;
  if (e1 < 384) { int r = e1 / 6, p = e1 - r * 6; dst1 = &Ks[r][p * 8]; off1 = r * 48 + p * 8; v1 = false; }
  else          { int i = e1 - 384; int d = i >> 3, p = i & 7; dst1 = &Vt[d][p * 8]; off1 = d * 1024 + p * 8; v1 = true; }
  int i2 = tid + 512 - 384;
  int d2 = i2 >> 3, p2 = i2 & 7;
  __bf16* dst2 = &Vt[d2][p2 * 8];
  int off2 = d2 * 1024 + p2 * 8;

  f32x4 accA[3] = {}, accB[3] = {};
  f32x4 laccA = {}, laccB = {};
  bf16x8 ones;
#pragma unroll
  for (int j = 0; j < 8; j++) ones[j] = (__bf16)1.0f;

  for (int kt = 0; kt < 16; kt++) {
    __syncthreads();
    const __bf16* kbt = kb + (size_t)kt * 3072;
    const __bf16* vbt = vb + kt * 64;
    *(bf16x8*)dst0 = *(const bf16x8*)(kbt + off0);
    *(bf16x8*)dst1 = *(const bf16x8*)((v1 ? vbt : kbt) + off1);
    *(bf16x8*)dst2 = *(const bf16x8*)(vbt + off2);
    __syncthreads();

#pragma unroll
    for (int f = 0; f < 4; f++) {
      bf16x8 ka0 = *(const bf16x8*)&Ks[f * 16 + c][g * 8];
      bf16x8 ka1 = *(const bf16x8*)&Ks[f * 16 + c][32 + g * 8];
      f32x4 za = {}, zb = {};
      za = __builtin_amdgcn_mfma_f32_16x16x32_bf16(ka0, qb0a, za, 0, 0, 0);
      f32x4 sa = __builtin_amdgcn_mfma_f32_16x16x32_bf16(ka1, qb1a, za, 0, 0, 0);
      zb = __builtin_amdgcn_mfma_f32_16x16x32_bf16(ka0, qb0b, zb, 0, 0, 0);
      f32x4 sb = __builtin_amdgcn_mfma_f32_16x16x32_bf16(ka1, qb1b, zb, 0, 0, 0);
      bf16x4 pka = { (__bf16)__builtin_amdgcn_exp2f(sa[0]), (__bf16)__builtin_amdgcn_exp2f(sa[1]),
                     (__bf16)__builtin_amdgcn_exp2f(sa[2]), (__bf16)__builtin_amdgcn_exp2f(sa[3]) };
      bf16x4 pkb = { (__bf16)__builtin_amdgcn_exp2f(sb[0]), (__bf16)__builtin_amdgcn_exp2f(sb[1]),
                     (__bf16)__builtin_amdgcn_exp2f(sb[2]), (__bf16)__builtin_amdgcn_exp2f(sb[3]) };
      *(bf16x4*)&Ps[w][0][c][f * 16 + 4 * g] = pka;
      *(bf16x4*)&Ps[w][1][c][f * 16 + 4 * g] = pkb;
    }
    bf16x8 pa0a = *(const bf16x8*)&Ps[w][0][c][g * 8];
    bf16x8 pa1a = *(const bf16x8*)&Ps[w][0][c][32 + g * 8];
    bf16x8 pa0b = *(const bf16x8*)&Ps[w][1][c][g * 8];
    bf16x8 pa1b = *(const bf16x8*)&Ps[w][1][c][32 + g * 8];
#pragma unroll
    for (int t = 0; t < 3; t++) {
      bf16x8 vb0 = *(const bf16x8*)&Vt[t * 16 + c][g * 8];
      bf16x8 vb1 = *(const bf16x8*)&Vt[t * 16 + c][32 + g * 8];
      accA[t] = __builtin_amdgcn_mfma_f32_16x16x32_bf16(pa0a, vb0, accA[t], 0, 0, 0);
      accA[t] = __builtin_amdgcn_mfma_f32_16x16x32_bf16(pa1a, vb1, accA[t], 0, 0, 0);
      accB[t] = __builtin_amdgcn_mfma_f32_16x16x32_bf16(pa0b, vb0, accB[t], 0, 0, 0);
      accB[t] = __builtin_amdgcn_mfma_f32_16x16x32_bf16(pa1b, vb1, accB[t], 0, 0, 0);
    }
    laccA = __builtin_amdgcn_mfma_f32_16x16x32_bf16(pa0a, ones, laccA, 0, 0, 0);
    laccA = __builtin_amdgcn_mfma_f32_16x16x32_bf16(pa1a, ones, laccA, 0, 0, 0);
    laccB = __builtin_amdgcn_mfma_f32_16x16x32_bf16(pa0b, ones, laccB, 0, 0, 0);
    laccB = __builtin_amdgcn_mfma_f32_16x16x32_bf16(pa1b, ones, laccB, 0, 0, 0);
  }
  float linvA[4], linvB[4];
#pragma unroll
  for (int r = 0; r < 4; r++) { linvA[r] = 1.f / laccA[r]; linvB[r] = 1.f / laccB[r]; }
  int b = bh >> 3, hh = bh & 7;
#pragma unroll
  for (int t = 0; t < 3; t++)
#pragma unroll
    for (int r = 0; r < 4; r++) {
      size_t rowA = (size_t)(b * SEQ + q0 + w * 16 + 4 * g + r);
      ao[rowA * DMODEL + hh * 48 + t * 16 + c] = (__bf16)(accA[t][r] * linvA[r]);
      ao[(rowA + 64) * DMODEL + hh * 48 + t * 16 + c] = (__bf16)(accB[t][r] * linvB[r]);
    }
}

// ---------------- gating: block = 32 tokens (512 blocks), block-aggregated atomics ----
__global__ __launch_bounds__(256) void gate_kernel(const __bf16* __restrict__ xnb,
    const float* __restrict__ gw, int* __restrict__ counts, float* __restrict__ sum_probs,
    int* __restrict__ tok_list, float* __restrict__ gate_list) {
  __shared__ float Gs[NEXP][DMODEL];
  __shared__ float simp[NEXP];
  __shared__ int hist[NEXP], basep[NEXP];
  __shared__ unsigned char tokE[32][2];
  __shared__ float tokG[32][2];
  __shared__ short rankS[32][2];
  int tid = threadIdx.x;
  for (int i = tid; i < DMODEL * NEXP; i += 256) {
    int d = i >> 3, e2 = i & 7;
    Gs[e2][d] = gw[i];
  }
  if (tid < NEXP) { simp[tid] = 0.f; hist[tid] = 0; }
  __syncthreads();
  int w = tid >> 6, lane = tid & 63;
  int tbase = blockIdx.x * 32 + w * 8;
  float impacc[NEXP] = {};
  for (int tt = 0; tt < 8; tt++) {
    int t = tbase + tt;
    float p[NEXP] = {};
#pragma unroll
    for (int j = 0; j < 6; j++) {
      int d = lane + 64 * j;
      float xv = (float)xnb[(size_t)t * DMODEL + d];
#pragma unroll
      for (int e2 = 0; e2 < NEXP; e2++) p[e2] += xv * Gs[e2][d];
    }
#pragma unroll
    for (int off = 32; off; off >>= 1)
#pragma unroll
      for (int e2 = 0; e2 < NEXP; e2++) p[e2] += __shfl_xor(p[e2], off);
    float mx = p[0];
#pragma unroll
    for (int e2 = 1; e2 < NEXP; e2++) mx = fmaxf(mx, p[e2]);
    float s = 0.f;
#pragma unroll
    for (int e2 = 0; e2 < NEXP; e2++) { p[e2] = __expf(p[e2] - mx); s += p[e2]; }
    float inv = 1.f / s;
#pragma unroll
    for (int e2 = 0; e2 < NEXP; e2++) { p[e2] *= inv; impacc[e2] += p[e2]; }
    int i0 = 0; float v0 = p[0];
#pragma unroll
    for (int e2 = 1; e2 < NEXP; e2++) if (p[e2] > v0) { v0 = p[e2]; i0 = e2; }
    int i1 = -1; float v1 = -INFINITY;
#pragma unroll
    for (int e2 = 0; e2 < NEXP; e2++) if (e2 != i0 && p[e2] > v1) { v1 = p[e2]; i1 = e2; }
    if (lane == 0) {
      float gsum = v0 + v1;
      int r0 = atomicAdd(&hist[i0], 1);
      int r1 = atomicAdd(&hist[i1], 1);
      int sl = w * 8 + tt;
      tokE[sl][0] = (unsigned char)i0; tokE[sl][1] = (unsigned char)i1;
      tokG[sl][0] = v0 / gsum;         tokG[sl][1] = v1 / gsum;
      rankS[sl][0] = (short)r0;        rankS[sl][1] = (short)r1;
    }
  }
  if (lane == 0)
#pragma unroll
    for (int e2 = 0; e2 < NEXP; e2++) atomicAdd(&simp[e2], impacc[e2]);
  __syncthreads();
  if (tid < NEXP) {
    basep[tid] = atomicAdd(&counts[tid], hist[tid]);
    atomicAdd(&sum_probs[tid], simp[tid]);
  }
  __syncthreads();
  int t0 = blockIdx.x * 32;
  if (tid < 64) {
    int sl = tid >> 1, a = tid & 1;
    int e2 = tokE[sl][a];
    int pos = basep[e2] + rankS[sl][a];
    tok_list[e2 * TOKENS + pos] = (t0 + sl) | (a << 16);
    gate_list[e2 * TOKENS + pos] = tokG[sl][a];
  }
}

// ---------------- attention-pool head, split for parallelism ----------------
__global__ __launch_bounds__(256) void head1_kernel(const float* __restrict__ h,
    const float* __restrict__ att_w, const float* __restrict__ att_b,
    float* __restrict__ logits) {
  int tid = threadIdx.x;
  int w = tid >> 6, lane = tid & 63;
  float4 aw0 = *(const float4*)&att_w[lane * 4];
  float2 aw1 = *(const float2*)&att_w[256 + lane * 2];
  float ab = att_b[0];
  for (int i = w; i < 32; i += 4) {
    int t = blockIdx.x * 32 + i;
    const float* hr = h + (size_t)t * DMODEL;
    float4 v4 = *(const float4*)&hr[lane * 4];
    float2 v2 = *(const float2*)&hr[256 + lane * 2];
    float dot = v4.x * aw0.x + v4.y * aw0.y + v4.z * aw0.z + v4.w * aw0.w
              + v2.x * aw1.x + v2.y * aw1.y;
#pragma unroll
    for (int off = 32; off; off >>= 1) dot += __shfl_xor(dot, off);
    if (lane == 0) logits[t] = dot + ab;
  }
}

__global__ __launch_bounds__(256) void head2_kernel(float* __restrict__ logits) {
  int b = blockIdx.x, tid = threadIdx.x;
  int w = tid >> 6, lane = tid & 63;
  float* lb = logits + b * SEQ;
  __shared__ float red[4];
  float lv[4];
  float mx = -INFINITY;
#pragma unroll
  for (int i = 0; i < 4; i++) { lv[i] = lb[tid + 256 * i]; mx = fmaxf(mx, lv[i]); }
#pragma unroll
  for (int off = 32; off; off >>= 1) mx = fmaxf(mx, __shfl_xor(mx, off));
  if (lane == 0) red[w] = mx;
  __syncthreads();
  mx = fmaxf(fmaxf(red[0], red[1]), fmaxf(red[2], red[3]));
  __syncthreads();
  float s = 0.f;
#pragma unroll
  for (int i = 0; i < 4; i++) { lv[i] = __expf(lv[i] - mx); s += lv[i]; }
#pragma unroll
  for (int off = 32; off; off >>= 1) s += __shfl_xor(s, off);
  if (lane == 0) red[w] = s;
  __syncthreads();
  float inv = 1.f / (red[0] + red[1] + red[2] + red[3]);
#pragma unroll
  for (int i = 0; i < 4; i++) lb[tid + 256 * i] = lv[i] * inv;
}

__global__ __launch_bounds__(256) void head3a_kernel(const float* __restrict__ h,
    const float* __restrict__ wnorm, float* __restrict__ partial) {
  int b = blockIdx.x, dc = blockIdx.y, sc = blockIdx.z;
  int tid = threadIdx.x;
  int d = tid & 63, sg = tid >> 6;
  const float* hb = h + (size_t)b * SEQ * DMODEL + dc * 64 + d;
  const float* wb = wnorm + b * SEQ + sc * 64;
  float acc = 0.f;
  int s0 = sc * 64 + sg * 16;
#pragma unroll
  for (int i = 0; i < 16; i++)
    acc += wb[sg * 16 + i] * hb[(size_t)(s0 + i) * DMODEL];
  __shared__ float red[256];
  red[tid] = acc;
  __syncthreads();
  if (sg == 0)
    partial[(((size_t)b * 6 + dc) * 16 + sc) * 64 + d] =
        red[d] + red[64 + d] + red[128 + d] + red[192 + d];
}

__global__ void head3b_kernel(const float* __restrict__ partial,
    const float* __restrict__ head_w, float* __restrict__ part) {
  int b = blockIdx.x, dc = blockIdx.y;
  int d = threadIdx.x;
  const float* pp = partial + (((size_t)b * 6 + dc) * 16) * 64 + d;
  float pooled = 0.f;
#pragma unroll
  for (int sc = 0; sc < 16; sc++) pooled += pp[sc * 64];
  float pd = pooled * head_w[dc * 64 + d];
#pragma unroll
  for (int off = 32; off; off >>= 1) pd += __shfl_xor(pd, off);
  if (d == 0) part[b * 6 + dc] = pd;
}

__global__ void head4_kernel(const float* __restrict__ part,
                             const float* __restrict__ head_b, float* __restrict__ out) {
  int b = threadIdx.x;
  if (b < 16) {
    float s = head_b[0];
#pragma unroll
    for (int dc = 0; dc < 6; dc++) s += part[b * 6 + dc];
    out[b] = s;
  }
}

// ---------------- launch ----------------
extern "C" void kernel_launch(void* const* d_in, const int* in_sizes, int n_in,
                              void* d_out, int out_size, void* d_ws, size_t ws_size,
                              hipStream_t stream) {
  (void)in_sizes; (void)n_in; (void)out_size; (void)ws_size;
  const float* x      = (const float*)d_in[0];
  const float* proj_w = (const float*)d_in[1];
  const float* proj_b = (const float*)d_in[2];
  const float* qkv_w  = (const float*)d_in[3];
  const float* qkv_b  = (const float*)d_in[4];
  const float* out_w  = (const float*)d_in[5];
  const float* out_b  = (const float*)d_in[6];
  const float* n1_s   = (const float*)d_in[7];
  const float* n1_b   = (const float*)d_in[8];
  const float* n2_s   = (const float*)d_in[9];
  const float* n2_b   = (const float*)d_in[10];
  const float* gate_w = (const float*)d_in[11];
  const float* e_w1   = (const float*)d_in[12];
  const float* e_b1   = (const float*)d_in[13];
  const float* e_w2   = (const float*)d_in[14];
  const float* e_b2   = (const float*)d_in[15];
  const float* att_w  = (const float*)d_in[16];
  const float* att_b  = (const float*)d_in[17];
  const float* head_w = (const float*)d_in[18];
  const float* head_b = (const float*)d_in[19];
  float* out = (float*)d_out;

  char* wsb = (char*)d_ws;
  float*  h    = (float*)(wsb);
  __bf16* xnb  = (__bf16*)(wsb + 25165824);
  __bf16* aob  = (__bf16*)(wsb + 37748736);
  __bf16* ab   = (__bf16*)(wsb + 25165824);        // [2][16384][384] aliases xnb+aob
  __bf16* uni  = (__bf16*)(wsb + 50331648);        // qkv-major region / a1b
  __bf16* Qh   = uni;                              // [128][1024][48]
  __bf16* Khd  = (__bf16*)(wsb + 62914560);
  __bf16* VTh  = (__bf16*)(wsb + 75497472);
  __bf16* qkvWt = (__bf16*)(wsb + 101449728);   // [3][1152][384]
  __bf16* outWt = (__bf16*)(wsb + 104103936);   // [3][384][384]
  __bf16* e1Wt  = (__bf16*)(wsb + 104988672);   // [3*8][768][384]
  __bf16* e2Wt  = (__bf16*)(wsb + 119144448);   // [3*8][384][768]
  char* sm = wsb + 133300224;
  int*   counts_all = (int*)(sm);                  // [3][8]
  float* sp_all     = (float*)(sm + 128);          // [3][8]
  int*   tok_list  = (int*)(sm + 256);
  float* gate_list = (float*)(sm + 256 + 524288);
  float* logits    = (float*)(sm + 1048832);
  float* part      = (float*)(sm + 1048832 + 65536);
  float* partial   = (float*)(sm + 1048832 + 131072);   // [16][6][16][64]

  convw_kernel<<<dim3(36, 12, 3), 256, 0, stream>>>(qkv_w, qkvWt, 384, 1152);
  convw_kernel<<<dim3(12, 12, 3), 256, 0, stream>>>(out_w, outWt, 384, 384);
  convw_kernel<<<dim3(24, 12, 24), 256, 0, stream>>>(e_w1, e1Wt, 384, 768);
  convw_kernel<<<dim3(12, 24, 24), 256, 0, stream>>>(e_w2, e2Wt, 768, 384);

  proj_kernel<<<TOKENS * DMODEL / 256, 256, 0, stream>>>(x, proj_w, proj_b, h);
  ln_kernel<<<TOKENS, 384, 0, stream>>>(h, xnb, n1_s, n1_b, nullptr, nullptr);

  for (int l = 0; l < NL; l++) {
    int*   counts = counts_all + l * NEXP;
    float* sp     = sp_all + l * NEXP;
    mgemm_kernel<0><<<dim3(9, 128), 256, 0, stream>>>(
        xnb, qkvWt + (size_t)l * 1152 * 384, qkv_b + l * 1152, nullptr, nullptr,
        Qh, Khd, VTh, nullptr, nullptr, nullptr, 1152, 384);
    attn_kernel<<<dim3(128, 8), 256, 0, stream>>>(Qh, Khd, VTh, aob);
    mgemm_kernel<1><<<dim3(3, 128), 256, 0, stream>>>(
        aob, outWt + (size_t)l * 384 * 384, out_b + l * 384, h, nullptr,
        nullptr, nullptr, nullptr, nullptr, nullptr, nullptr, 384, 384);
    // n2 LayerNorm also zeroes this layer's counts/sum_probs (block 0)
    ln_kernel<<<TOKENS, 384, 0, stream>>>(h, xnb, n2_s + l * DMODEL, n2_b + l * DMODEL,
                                          counts, sp);
    gate_kernel<<<512, 256, 0, stream>>>(xnb, gate_w + (size_t)l * DMODEL * NEXP,
                                         counts, sp, tok_list, gate_list);
    mgemm_kernel<2><<<dim3(6, 128, 8), 256, 0, stream>>>(
        xnb, e1Wt + (size_t)l * 8 * 768 * 384, e_b1 + l * 8 * FFDIM, nullptr, uni,
        nullptr, nullptr, nullptr, counts, tok_list, nullptr, 768, 384);
    mgemm_kernel<3><<<dim3(3, 128, 8), 256, 0, stream>>>(
        uni, e2Wt + (size_t)l * 8 * 384 * 768, e_b2 + l * 8 * DMODEL, nullptr, ab,
        nullptr, nullptr, nullptr, counts, tok_list, gate_list, 384, 768);
    if (l + 1 < NL) {
      lncomb_kernel<<<TOKENS, 384, 0, stream>>>(h, ab, xnb,
          n1_s + (l + 1) * DMODEL, n1_b + (l + 1) * DMODEL);
    } else {
      combine_kernel<<<TOKENS * DMODEL / (256 * 8), 256, 0, stream>>>(h, ab);
    }
  }

  head1_kernel<<<512, 256, 0, stream>>>(h, att_w, att_b, logits);
  head2_kernel<<<16, 256, 0, stream>>>(logits);
  head3a_kernel<<<dim3(16, 6, 16), 256, 0, stream>>>(h, logits, partial);
  head3b_kernel<<<dim3(16, 6), 64, 0, stream>>>(partial, head_w, part);
  head4_kernel<<<1, 64, 0, stream>>>(part, head_b, out);
  finalize_kernel<<<1, 1, 0, stream>>>(counts_all, sp_all, out);
}